// Round 9
// baseline (152.686 us; speedup 1.0000x reference)
//
#include <hip/hip_runtime.h>
#include <math.h>

#define NVIEW 8
#define CIN   32
#define HF    128
#define WF    128
#define C1    32
#define C2    16
#define C3    8
#define RESO  64
#define PLANE (HF*WF)          // 16384 texels per (v,q) plane, float4 units

typedef _Float16 half8_t  __attribute__((ext_vector_type(8)));
typedef _Float16 half2_t  __attribute__((ext_vector_type(2)));
typedef float    floatx4  __attribute__((ext_vector_type(4)));

static __device__ __forceinline__ float vox_coord(int idx, float b) {
    const float VOXEL = (float)(0.3 / 64.0);
    const float HALFV = (float)(0.3 / 128.0);
    return (float)idx * VOXEL + HALFV + b;
}

// mats rows 0/1 pre-scaled by 63.5/img_w, 63.5/img_h so ix,iy come straight out.
static __device__ __forceinline__ void proj_ixiy(const float* M, float x, float y, float z,
                                                 float& ix, float& iy, float& zc) {
    float u  = fmaf(M[0], x, fmaf(M[1], y, fmaf(M[2],  z, M[3])));
    float vv = fmaf(M[4], x, fmaf(M[5], y, fmaf(M[6],  z, M[7])));
    zc       = fmaf(M[8], x, fmaf(M[9], y, fmaf(M[10], z, M[11])));
    float invz = __builtin_amdgcn_rcpf(zc);
    ix = u * invz;
    iy = vv * invz;
}

// wave-level LDS sync: each wave uses a private LDS slice; DS ops are in-order
// per wave, so only a lgkmcnt drain + compiler barrier is needed. No s_barrier.
static __device__ __forceinline__ void wave_lds_sync() {
    asm volatile("s_waitcnt lgkmcnt(0)" ::: "memory");
}

// ---- K1: G planar-quad + (block 512) prep of mats / fp16 weight frags ----
__global__ void __launch_bounds__(256) k_g(const float* __restrict__ feats,
                                           const float* __restrict__ W1,
                                           const float* __restrict__ b1,
                                           float4* __restrict__ G4,
                                           const float* __restrict__ Ks,
                                           const float* __restrict__ poses,
                                           const int* __restrict__ ihp,
                                           const int* __restrict__ iwp,
                                           const float* __restrict__ W2,
                                           const float* __restrict__ b2,
                                           const float* __restrict__ W3,
                                           const float* __restrict__ b3,
                                           float* __restrict__ mats,
                                           _Float16* __restrict__ w2f,
                                           _Float16* __restrict__ w3f,
                                           float* __restrict__ b2f,
                                           float* __restrict__ b3f) {
    if (blockIdx.x == 512) {
        int t = threadIdx.x;
        if (t < NVIEW * 12) {
            int v = t / 12, rc = t % 12, r = rc / 4, c = rc % 4;
            const float* K = Ks + v * 9;
            const float* P = poses + v * 12;
            float s = K[r*3+0]*P[0*4+c] + K[r*3+1]*P[1*4+c] + K[r*3+2]*P[2*4+c];
            float sc = (r == 0) ? 63.5f / (float)iwp[0]
                     : (r == 1) ? 63.5f / (float)ihp[0] : 1.0f;
            mats[v*12 + r*4 + c] = s * sc;
        }
        if (t < 64) {
            int n = t & 15, g = t >> 4;
            // B-frag for mfma_f32_16x16x32_f16: lane holds B[k=8g+j][n], j=0..7
#pragma unroll
            for (int jj = 0; jj < 8; jj++) {
                int kk = 8 * g + jj;
                w2f[t*8 + jj] = (_Float16)W2[kk * C2 + n];
                float w3v = (kk < C2 && n < C3) ? W3[kk * C3 + n] : 0.0f;  // K,N zero-pad
                w3f[t*8 + jj] = (_Float16)w3v;
            }
            b2f[t] = b2[n];
            b3f[t] = (n < C3) ? b3[n] : 0.0f;
        }
        return;
    }
    int t = blockIdx.x * 256 + threadIdx.x;    // NVIEW*HF*WF = 131072 threads
    int pix = t & (PLANE - 1);
    int v = t >> 14;
    const float* fp = feats + ((size_t)v * CIN) * PLANE + pix;
    float f[CIN];
#pragma unroll
    for (int c = 0; c < CIN; c++) f[c] = fp[(size_t)c * PLANE];
    float g[C1];
#pragma unroll
    for (int jj = 0; jj < C1; jj++) g[jj] = b1[jj];
#pragma unroll
    for (int c = 0; c < CIN; c++) {
        float fc = f[c];
#pragma unroll
        for (int jj = 0; jj < C1; jj++) g[jj] = fmaf(fc, W1[c*C1 + jj], g[jj]);
    }
#pragma unroll
    for (int q = 0; q < C1/4; q++)
        G4[((size_t)(v * 8 + q)) * PLANE + pix] =
            make_float4(g[4*q], g[4*q+1], g[4*q+2], g[4*q+3]);
}

// ---- K2: each wave = HALF a 64-voxel column (32 points) -> 8192 waves.
// Full-column mask per wave via one lane=point projection + __ballot (bit p =
// point p, popcount = msum exactly). Blend: lane (m,g) builds the MFMA A-frag
// (ch 8g..8g+7 of local point T*16+m) in registers; layers 2+3 on MFMA. ----
__global__ void __launch_bounds__(256) k_main(
    const float4* __restrict__ G4,
    const float* __restrict__ mats, const float* __restrict__ bbox,
    const _Float16* __restrict__ w2f, const _Float16* __restrict__ w3f,
    const float* __restrict__ b2f, const float* __restrict__ b3f,
    float* __restrict__ out) {
    __shared__ __align__(16) _Float16 h2s[4][32 * 24];   // per-wave [32 pts][24 ch]

    int tid  = threadIdx.x;
    int wv   = tid >> 6;                   // 4 waves: 2 columns x 2 halves
    int lane = tid & 63;
    int col  = blockIdx.x * 2 + (wv >> 1); // 4096 columns: (k<<6)|j
    int half = wv & 1;
    int w32  = half * 32;
    int j  = col & 63;
    int kz = col >> 6;
    _Float16* h2b = h2s[wv];

    int m = lane & 15, g = lane >> 4;
    float y = vox_coord(j, bbox[1]);
    float z = vox_coord(kz, bbox[2]);
    float xmask = vox_coord(lane, bbox[0]);           // full-column mask point
    float xb[2];
    xb[0] = vox_coord(w32 + m,      bbox[0]);         // blend point T=0
    xb[1] = vox_coord(w32 + 16 + m, bbox[0]);         // blend point T=1

    half8_t w2frag = *(const half8_t*)(w2f + lane * 8);
    half8_t w3frag = *(const half8_t*)(w3f + lane * 8);
    float b2c = b2f[lane];
    float b3c = b3f[lane];
    floatx4 cb2 = {b2c, b2c, b2c, b2c};
    floatx4 cb3 = {b3c, b3c, b3c, b3c};

    float M1[8], Msq[8], S16[8];
#pragma unroll
    for (int c = 0; c < 8; c++) { M1[c] = 0.0f; Msq[c] = 0.0f; S16[c] = 0.0f; }

#pragma unroll 1
    for (int v = 0; v < NVIEW; v++) {
        const float* M = mats + v * 12;
        const float4* Gv = G4 + (size_t)v * 8 * PLANE;

        // full-column mask: lane == point index i
        float ixm, iym, zcm;
        proj_ixiy(M, xmask, y, z, ixm, iym, zcm);
        bool inbm = (ixm >= 0.0f) && (ixm <= (float)(WF-1)) &&
                    (iym >= 0.0f) && (iym <= (float)(HF-1)) && (zcm > 0.0f);
        unsigned long long bal = __ballot(inbm);      // bit p = point p's mask
        float msr = __builtin_amdgcn_rcpf((float)__popcll(bal) + 1e-8f);

        floatx4 c2v[2];
#pragma unroll
        for (int T = 0; T < 2; T++) {
            float ix, iy, zc;
            proj_ixiy(M, xb[T], y, z, ix, iy, zc);

            float fx0 = floorf(ix), fy0 = floorf(iy);
            float fx1 = fx0 + 1.0f, fy1 = fy0 + 1.0f;
            int cx0 = (int)fminf(fmaxf(fx0, 0.0f), (float)(WF-1));
            int cx1 = (int)fminf(fmaxf(fx1, 0.0f), (float)(WF-1));
            int cy0 = (int)fminf(fmaxf(fy0, 0.0f), (float)(HF-1));
            int cy1 = (int)fminf(fmaxf(fy1, 0.0f), (float)(HF-1));
            float wnw = (fx1 - ix) * (fy1 - iy);
            float wne = (ix - fx0) * (fy1 - iy);
            float wsw = (fx1 - ix) * (iy - fy0);
            float wse = (ix - fx0) * (iy - fy0);

            int t00 = cy0 * WF + cx0, t01 = cy0 * WF + cx1;
            int t10 = cy1 * WF + cx0, t11 = cy1 * WF + cx1;
            const float4* P0 = Gv + (2*g)     * PLANE;
            const float4* P1 = Gv + (2*g + 1) * PLANE;
            float4 a0 = P0[t00], b0 = P0[t01], c0 = P0[t10], d0 = P0[t11];
            float4 a1 = P1[t00], b1v = P1[t01], c1 = P1[t10], d1 = P1[t11];

            float e0 = fmaxf(fmaf(wnw, a0.x, fmaf(wne, b0.x, fmaf(wsw, c0.x, wse * d0.x))), 0.0f);
            float e1 = fmaxf(fmaf(wnw, a0.y, fmaf(wne, b0.y, fmaf(wsw, c0.y, wse * d0.y))), 0.0f);
            float e2 = fmaxf(fmaf(wnw, a0.z, fmaf(wne, b0.z, fmaf(wsw, c0.z, wse * d0.z))), 0.0f);
            float e3 = fmaxf(fmaf(wnw, a0.w, fmaf(wne, b0.w, fmaf(wsw, c0.w, wse * d0.w))), 0.0f);
            float e4 = fmaxf(fmaf(wnw, a1.x, fmaf(wne, b1v.x, fmaf(wsw, c1.x, wse * d1.x))), 0.0f);
            float e5 = fmaxf(fmaf(wnw, a1.y, fmaf(wne, b1v.y, fmaf(wsw, c1.y, wse * d1.y))), 0.0f);
            float e6 = fmaxf(fmaf(wnw, a1.z, fmaf(wne, b1v.z, fmaf(wsw, c1.z, wse * d1.z))), 0.0f);
            float e7 = fmaxf(fmaf(wnw, a1.w, fmaf(wne, b1v.w, fmaf(wsw, c1.w, wse * d1.w))), 0.0f);

            union { half8_t h8; half2_t h2[4]; } u;
            u.h2[0] = __builtin_bit_cast(half2_t, __builtin_amdgcn_cvt_pkrtz(e0, e1));
            u.h2[1] = __builtin_bit_cast(half2_t, __builtin_amdgcn_cvt_pkrtz(e2, e3));
            u.h2[2] = __builtin_bit_cast(half2_t, __builtin_amdgcn_cvt_pkrtz(e4, e5));
            u.h2[3] = __builtin_bit_cast(half2_t, __builtin_amdgcn_cvt_pkrtz(e6, e7));

            c2v[T] = __builtin_amdgcn_mfma_f32_16x16x32_f16(u.h8, w2frag, cb2, 0, 0, 0);
        }

        // relu + cvt in C-layout (lane&15 = out-channel n), store h2 [pt][ch]
        wave_lds_sync();   // guard WAR vs previous view's h2 reads (cheap)
#pragma unroll
        for (int T = 0; T < 2; T++) {
#pragma unroll
            for (int r = 0; r < 4; r++) {
                float vv = fmaxf(c2v[T][r], 0.0f);
                h2b[(T*16 + g*4 + r) * 24 + m] = (_Float16)vv;
            }
        }
        wave_lds_sync();

        // layer 3: A = h2 rows (lane&15 = local point-row), B = 0-padded W3, C = bias
#pragma unroll
        for (int T = 0; T < 2; T++) {
            half8_t a3 = *(const half8_t*)(h2b + (T*16 + m) * 24 + (g & 1) * 8);
            floatx4 c3 = __builtin_amdgcn_mfma_f32_16x16x32_f16(a3, w3frag, cb3, 0, 0, 0);
#pragma unroll
            for (int r = 0; r < 4; r++) {
                int gp = w32 + T*16 + g*4 + r;            // global point in column
                float w = ((bal >> gp) & 1ull) ? msr : 0.0f;
                float val = c3[r];
                float t1 = w * val;
                S16[T*4+r] += w;
                M1[T*4+r]  += t1;
                Msq[T*4+r]  = fmaf(t1, val, Msq[T*4+r]);
            }
        }
    }

    // epilogue: lane (m<8, g) stores points w32+T*16+g*4..+3, planes m / m+8
    if (m < C3) {
        size_t base = (size_t)col * 64 + w32;
#pragma unroll
        for (int T = 0; T < 2; T++) {
            float4 mn, vr;
            mn.x = M1[T*4+0]; mn.y = M1[T*4+1]; mn.z = M1[T*4+2]; mn.w = M1[T*4+3];
            vr.x = fmaf(mn.x*mn.x, S16[T*4+0]-2.0f, Msq[T*4+0]);
            vr.y = fmaf(mn.y*mn.y, S16[T*4+1]-2.0f, Msq[T*4+1]);
            vr.z = fmaf(mn.z*mn.z, S16[T*4+2]-2.0f, Msq[T*4+2]);
            vr.w = fmaf(mn.w*mn.w, S16[T*4+3]-2.0f, Msq[T*4+3]);
            size_t ob = base + T*16 + g*4;
            *(float4*)(out + (size_t)m       * 262144 + ob) = mn;
            *(float4*)(out + (size_t)(m + 8) * 262144 + ob) = vr;
        }
    }
}

// ---- launch ----
extern "C" void kernel_launch(void* const* d_in, const int* in_sizes, int n_in,
                              void* d_out, int out_size, void* d_ws, size_t ws_size,
                              hipStream_t stream) {
    const float* feats = (const float*)d_in[0];
    const float* poses = (const float*)d_in[1];
    const float* Ks    = (const float*)d_in[2];
    const float* bbox  = (const float*)d_in[3];
    const int*   img_h = (const int*)d_in[4];
    const int*   img_w = (const int*)d_in[5];
    const float* W1    = (const float*)d_in[6];
    const float* b1    = (const float*)d_in[7];
    const float* W2    = (const float*)d_in[8];
    const float* b2    = (const float*)d_in[9];
    const float* W3    = (const float*)d_in[10];
    const float* b3    = (const float*)d_in[11];
    float* out = (float*)d_out;
    float* ws  = (float*)d_ws;

    float*     mats = ws;                        // 96 floats (pad to 128)
    _Float16*  w2f  = (_Float16*)(ws + 128);     // 512 halves (256 floats)
    _Float16*  w3f  = (_Float16*)(ws + 384);     // 512 halves
    float*     b2f  = ws + 640;                  // 64
    float*     b3f  = ws + 704;                  // 64
    float4*    G4   = (float4*)(ws + 768);       // 8*8*16384 float4 = 16 MB, 16B-aligned

    hipLaunchKernelGGL(k_g, dim3(513), dim3(256), 0, stream,
                       feats, W1, b1, G4, Ks, poses, img_h, img_w,
                       W2, b2, W3, b3, mats, w2f, w3f, b2f, b3f);
    hipLaunchKernelGGL(k_main, dim3(2048), dim3(256), 0, stream,
                       G4, mats, bbox, w2f, w3f, b2f, b3f, out);
}

// Round 10
// 139.926 us; speedup vs baseline: 1.0912x; 1.0912x over previous
//
#include <hip/hip_runtime.h>
#include <math.h>

#define NVIEW 8
#define CIN   32
#define HF    128
#define WF    128
#define C1    32
#define C2    16
#define C3    8
#define RESO  64
#define PLANE (HF*WF)          // 16384 texels per (v,q) plane, float4 units

typedef _Float16 half8_t  __attribute__((ext_vector_type(8)));
typedef _Float16 half2_t  __attribute__((ext_vector_type(2)));
typedef float    floatx4  __attribute__((ext_vector_type(4)));

static __device__ __forceinline__ float vox_coord(int idx, float b) {
    const float VOXEL = (float)(0.3 / 64.0);
    const float HALFV = (float)(0.3 / 128.0);
    return (float)idx * VOXEL + HALFV + b;
}

// mats rows 0/1 pre-scaled by 63.5/img_w, 63.5/img_h so ix,iy come straight out.
static __device__ __forceinline__ void proj_ixiy(const float* M, float x, float y, float z,
                                                 float& ix, float& iy, float& zc) {
    float u  = fmaf(M[0], x, fmaf(M[1], y, fmaf(M[2],  z, M[3])));
    float vv = fmaf(M[4], x, fmaf(M[5], y, fmaf(M[6],  z, M[7])));
    zc       = fmaf(M[8], x, fmaf(M[9], y, fmaf(M[10], z, M[11])));
    float invz = __builtin_amdgcn_rcpf(zc);
    ix = u * invz;
    iy = vv * invz;
}

// wave-level LDS sync: each wave uses a private LDS slice; DS ops are in-order
// per wave, so only a lgkmcnt drain + compiler barrier is needed. No s_barrier.
static __device__ __forceinline__ void wave_lds_sync() {
    asm volatile("s_waitcnt lgkmcnt(0)" ::: "memory");
}

// ---- K1: G planar-quad, 4-way channel-split (thread = texel x 8 channels),
// + (block 2048) prep of mats / fp16 weight frags. 8192 waves -> 8/SIMD. ----
__global__ void __launch_bounds__(256) k_g(const float* __restrict__ feats,
                                           const float* __restrict__ W1,
                                           const float* __restrict__ b1,
                                           float4* __restrict__ G4,
                                           const float* __restrict__ Ks,
                                           const float* __restrict__ poses,
                                           const int* __restrict__ ihp,
                                           const int* __restrict__ iwp,
                                           const float* __restrict__ W2,
                                           const float* __restrict__ b2,
                                           const float* __restrict__ W3,
                                           const float* __restrict__ b3,
                                           float* __restrict__ mats,
                                           _Float16* __restrict__ w2f,
                                           _Float16* __restrict__ w3f,
                                           float* __restrict__ b2f,
                                           float* __restrict__ b3f) {
    if (blockIdx.x == 2048) {
        int t = threadIdx.x;
        if (t < NVIEW * 12) {
            int v = t / 12, rc = t % 12, r = rc / 4, c = rc % 4;
            const float* K = Ks + v * 9;
            const float* P = poses + v * 12;
            float s = K[r*3+0]*P[0*4+c] + K[r*3+1]*P[1*4+c] + K[r*3+2]*P[2*4+c];
            float sc = (r == 0) ? 63.5f / (float)iwp[0]
                     : (r == 1) ? 63.5f / (float)ihp[0] : 1.0f;
            mats[v*12 + r*4 + c] = s * sc;
        }
        if (t < 64) {
            int n = t & 15, g = t >> 4;
            // B-frag for mfma_f32_16x16x32_f16: lane holds B[k=8g+j][n], j=0..7
#pragma unroll
            for (int jj = 0; jj < 8; jj++) {
                int kk = 8 * g + jj;
                w2f[t*8 + jj] = (_Float16)W2[kk * C2 + n];
                float w3v = (kk < C2 && n < C3) ? W3[kk * C3 + n] : 0.0f;  // K,N zero-pad
                w3f[t*8 + jj] = (_Float16)w3v;
            }
            b2f[t] = b2[n];
            b3f[t] = (n < C3) ? b3[n] : 0.0f;
        }
        return;
    }
    // 2048 blocks: [view(8)][group(4)][pixblk(64)]
    int bx = blockIdx.x;
    int pix = (bx & 63) * 256 + threadIdx.x;   // coalesced
    int grp = (bx >> 6) & 3;                   // 8-channel group
    int v   = bx >> 8;
    const float* fp = feats + ((size_t)v * CIN) * PLANE + pix;
    const float* W1g = W1 + grp * 8;
    float g[8];
#pragma unroll
    for (int jj = 0; jj < 8; jj++) g[jj] = b1[grp * 8 + jj];
#pragma unroll
    for (int c = 0; c < CIN; c++) {
        float fc = fp[(size_t)c * PLANE];
#pragma unroll
        for (int jj = 0; jj < 8; jj++) g[jj] = fmaf(fc, W1g[c*C1 + jj], g[jj]);
    }
    G4[((size_t)(v * 8 + grp*2 + 0)) * PLANE + pix] = make_float4(g[0], g[1], g[2], g[3]);
    G4[((size_t)(v * 8 + grp*2 + 1)) * PLANE + pix] = make_float4(g[4], g[5], g[6], g[7]);
}

// ---- K2 (R8 structure): block = 4 independent waves; each wave = one 64-voxel
// column. Lane (m,g) blends ch 8g..8g+7 of point T*16+m straight into the MFMA
// A-frag (no h1 LDS); layers 2+3 on MFMA; msum via ballot. ----
__global__ void __launch_bounds__(256) k_main(
    const float4* __restrict__ G4,
    const float* __restrict__ mats, const float* __restrict__ bbox,
    const _Float16* __restrict__ w2f, const _Float16* __restrict__ w3f,
    const float* __restrict__ b2f, const float* __restrict__ b3f,
    float* __restrict__ out) {
    __shared__ __align__(16) _Float16 h2s[4][64 * 24];   // per-wave [point][ch] slice

    int tid  = threadIdx.x;
    int wv   = tid >> 6;
    int lane = tid & 63;
    int col  = blockIdx.x * 4 + wv;        // 4096 columns: (k<<6)|j
    int j  = col & 63;
    int kz = col >> 6;
    _Float16* h2b = h2s[wv];

    int m = lane & 15, g = lane >> 4;
    float y = vox_coord(j, bbox[1]);
    float z = vox_coord(kz, bbox[2]);

    half8_t w2frag = *(const half8_t*)(w2f + lane * 8);
    half8_t w3frag = *(const half8_t*)(w3f + lane * 8);
    float b2c = b2f[lane];
    float b3c = b3f[lane];
    floatx4 cb2 = {b2c, b2c, b2c, b2c};
    floatx4 cb3 = {b3c, b3c, b3c, b3c};

    float M1[16], Msq[16], S16[16];
#pragma unroll
    for (int c = 0; c < 16; c++) { M1[c] = 0.0f; Msq[c] = 0.0f; S16[c] = 0.0f; }

#pragma unroll 1
    for (int v = 0; v < NVIEW; v++) {
        const float* M = mats + v * 12;
        const float4* Gv = G4 + (size_t)v * 8 * PLANE;

        floatx4 c2v[4];
        unsigned int ballo[4];
        int popc = 0;

#pragma unroll
        for (int T = 0; T < 4; T++) {
            int ipt = T * 16 + m;                      // point index in column
            float x = vox_coord(ipt, bbox[0]);
            float ix, iy, zc;
            proj_ixiy(M, x, y, z, ix, iy, zc);

            float fx0 = floorf(ix), fy0 = floorf(iy);
            float fx1 = fx0 + 1.0f, fy1 = fy0 + 1.0f;
            bool inb = (ix >= 0.0f) && (ix <= (float)(WF-1)) &&
                       (iy >= 0.0f) && (iy <= (float)(HF-1)) && (zc > 0.0f);
            int cx0 = (int)fminf(fmaxf(fx0, 0.0f), (float)(WF-1));
            int cx1 = (int)fminf(fmaxf(fx1, 0.0f), (float)(WF-1));
            int cy0 = (int)fminf(fmaxf(fy0, 0.0f), (float)(HF-1));
            int cy1 = (int)fminf(fmaxf(fy1, 0.0f), (float)(HF-1));
            float wnw = (fx1 - ix) * (fy1 - iy);
            float wne = (ix - fx0) * (fy1 - iy);
            float wsw = (fx1 - ix) * (iy - fy0);
            float wse = (ix - fx0) * (iy - fy0);

            unsigned long long bal = __ballot(inb);    // 4 identical copies per point
            ballo[T] = (unsigned int)bal;              // bits 0..15 = g-group 0
            popc += __popcll(bal);

            int t00 = cy0 * WF + cx0, t01 = cy0 * WF + cx1;
            int t10 = cy1 * WF + cx0, t11 = cy1 * WF + cx1;
            const float4* P0 = Gv + (2*g)     * PLANE;
            const float4* P1 = Gv + (2*g + 1) * PLANE;
            float4 a0 = P0[t00], b0 = P0[t01], c0 = P0[t10], d0 = P0[t11];
            float4 a1 = P1[t00], b1v = P1[t01], c1 = P1[t10], d1 = P1[t11];

            float e0 = fmaxf(fmaf(wnw, a0.x, fmaf(wne, b0.x, fmaf(wsw, c0.x, wse * d0.x))), 0.0f);
            float e1 = fmaxf(fmaf(wnw, a0.y, fmaf(wne, b0.y, fmaf(wsw, c0.y, wse * d0.y))), 0.0f);
            float e2 = fmaxf(fmaf(wnw, a0.z, fmaf(wne, b0.z, fmaf(wsw, c0.z, wse * d0.z))), 0.0f);
            float e3 = fmaxf(fmaf(wnw, a0.w, fmaf(wne, b0.w, fmaf(wsw, c0.w, wse * d0.w))), 0.0f);
            float e4 = fmaxf(fmaf(wnw, a1.x, fmaf(wne, b1v.x, fmaf(wsw, c1.x, wse * d1.x))), 0.0f);
            float e5 = fmaxf(fmaf(wnw, a1.y, fmaf(wne, b1v.y, fmaf(wsw, c1.y, wse * d1.y))), 0.0f);
            float e6 = fmaxf(fmaf(wnw, a1.z, fmaf(wne, b1v.z, fmaf(wsw, c1.z, wse * d1.z))), 0.0f);
            float e7 = fmaxf(fmaf(wnw, a1.w, fmaf(wne, b1v.w, fmaf(wsw, c1.w, wse * d1.w))), 0.0f);

            union { half8_t h8; half2_t h2[4]; } u;
            u.h2[0] = __builtin_bit_cast(half2_t, __builtin_amdgcn_cvt_pkrtz(e0, e1));
            u.h2[1] = __builtin_bit_cast(half2_t, __builtin_amdgcn_cvt_pkrtz(e2, e3));
            u.h2[2] = __builtin_bit_cast(half2_t, __builtin_amdgcn_cvt_pkrtz(e4, e5));
            u.h2[3] = __builtin_bit_cast(half2_t, __builtin_amdgcn_cvt_pkrtz(e6, e7));

            c2v[T] = __builtin_amdgcn_mfma_f32_16x16x32_f16(u.h8, w2frag, cb2, 0, 0, 0);
        }

        // relu + cvt in C-layout (lane&15 = out-channel n), store h2 [pt][ch]
        wave_lds_sync();   // guard WAR vs previous view's h2 reads (cheap)
#pragma unroll
        for (int T = 0; T < 4; T++) {
#pragma unroll
            for (int r = 0; r < 4; r++) {
                float vv = fmaxf(c2v[T][r], 0.0f);
                h2b[(T*16 + g*4 + r) * 24 + m] = (_Float16)vv;
            }
        }
        wave_lds_sync();

        // layer 3: A = h2 rows (lane&15 = point-row), B = zero-padded W3, C = bias
        float msr = __builtin_amdgcn_rcpf((float)(popc >> 2) + 1e-8f);
#pragma unroll
        for (int T = 0; T < 4; T++) {
            half8_t a3 = *(const half8_t*)(h2b + (T*16 + m) * 24 + (g & 1) * 8);
            floatx4 c3 = __builtin_amdgcn_mfma_f32_16x16x32_f16(a3, w3frag, cb3, 0, 0, 0);
#pragma unroll
            for (int r = 0; r < 4; r++) {
                float w = ((ballo[T] >> (g*4 + r)) & 1u) ? msr : 0.0f;
                float val = c3[r];
                float t1 = w * val;
                S16[T*4+r] += w;
                M1[T*4+r]  += t1;
                Msq[T*4+r]  = fmaf(t1, val, Msq[T*4+r]);
            }
        }
    }

    // epilogue: lane (m<8, g) stores points T*16+g*4..+3, mean plane m, var plane m+8
    if (m < C3) {
        size_t base = (size_t)col * 64;
#pragma unroll
        for (int T = 0; T < 4; T++) {
            float4 mn, vr;
            mn.x = M1[T*4+0]; mn.y = M1[T*4+1]; mn.z = M1[T*4+2]; mn.w = M1[T*4+3];
            vr.x = fmaf(mn.x*mn.x, S16[T*4+0]-2.0f, Msq[T*4+0]);
            vr.y = fmaf(mn.y*mn.y, S16[T*4+1]-2.0f, Msq[T*4+1]);
            vr.z = fmaf(mn.z*mn.z, S16[T*4+2]-2.0f, Msq[T*4+2]);
            vr.w = fmaf(mn.w*mn.w, S16[T*4+3]-2.0f, Msq[T*4+3]);
            size_t ob = base + T*16 + g*4;
            *(float4*)(out + (size_t)m       * 262144 + ob) = mn;
            *(float4*)(out + (size_t)(m + 8) * 262144 + ob) = vr;
        }
    }
}

// ---- launch ----
extern "C" void kernel_launch(void* const* d_in, const int* in_sizes, int n_in,
                              void* d_out, int out_size, void* d_ws, size_t ws_size,
                              hipStream_t stream) {
    const float* feats = (const float*)d_in[0];
    const float* poses = (const float*)d_in[1];
    const float* Ks    = (const float*)d_in[2];
    const float* bbox  = (const float*)d_in[3];
    const int*   img_h = (const int*)d_in[4];
    const int*   img_w = (const int*)d_in[5];
    const float* W1    = (const float*)d_in[6];
    const float* b1    = (const float*)d_in[7];
    const float* W2    = (const float*)d_in[8];
    const float* b2    = (const float*)d_in[9];
    const float* W3    = (const float*)d_in[10];
    const float* b3    = (const float*)d_in[11];
    float* out = (float*)d_out;
    float* ws  = (float*)d_ws;

    float*     mats = ws;                        // 96 floats (pad to 128)
    _Float16*  w2f  = (_Float16*)(ws + 128);     // 512 halves (256 floats)
    _Float16*  w3f  = (_Float16*)(ws + 384);     // 512 halves
    float*     b2f  = ws + 640;                  // 64
    float*     b3f  = ws + 704;                  // 64
    float4*    G4   = (float4*)(ws + 768);       // 8*8*16384 float4 = 16 MB, 16B-aligned

    hipLaunchKernelGGL(k_g, dim3(2049), dim3(256), 0, stream,
                       feats, W1, b1, G4, Ks, poses, img_h, img_w,
                       W2, b2, W3, b3, mats, w2f, w3f, b2f, b3f);
    hipLaunchKernelGGL(k_main, dim3(1024), dim3(256), 0, stream,
                       G4, mats, bbox, w2f, w3f, b2f, b3f, out);
}

// Round 11
// 130.802 us; speedup vs baseline: 1.1673x; 1.0698x over previous
//
#include <hip/hip_runtime.h>
#include <math.h>

#define NVIEW 8
#define CIN   32
#define HF    128
#define WF    128
#define C1    32
#define C2    16
#define C3    8
#define RESO  64
#define PLANE (HF*WF)          // 16384 texels per (v,group) plane, uint4 units

typedef _Float16 half8_t  __attribute__((ext_vector_type(8)));
typedef _Float16 half2_t  __attribute__((ext_vector_type(2)));
typedef float    floatx4  __attribute__((ext_vector_type(4)));

static __device__ __forceinline__ float vox_coord(int idx, float b) {
    const float VOXEL = (float)(0.3 / 64.0);
    const float HALFV = (float)(0.3 / 128.0);
    return (float)idx * VOXEL + HALFV + b;
}

// mats rows 0/1 pre-scaled by 63.5/img_w, 63.5/img_h so ix,iy come straight out.
static __device__ __forceinline__ void proj_ixiy(const float* M, float x, float y, float z,
                                                 float& ix, float& iy, float& zc) {
    float u  = fmaf(M[0], x, fmaf(M[1], y, fmaf(M[2],  z, M[3])));
    float vv = fmaf(M[4], x, fmaf(M[5], y, fmaf(M[6],  z, M[7])));
    zc       = fmaf(M[8], x, fmaf(M[9], y, fmaf(M[10], z, M[11])));
    float invz = __builtin_amdgcn_rcpf(zc);
    ix = u * invz;
    iy = vv * invz;
}

// wave-level LDS sync: each wave uses a private LDS slice; DS ops are in-order
// per wave, so only a lgkmcnt drain + compiler barrier is needed. No s_barrier.
static __device__ __forceinline__ void wave_lds_sync() {
    asm volatile("s_waitcnt lgkmcnt(0)" ::: "memory");
}

// ---- K1: G in fp16, planar 8-channel groups: Gh[(v*4+grp)*PLANE + pix] = 16 B
// (8 halves, RTNE). 4-way channel-split (thread = texel x 8 channels) +
// (block 2048) prep of mats / fp16 weight frags. ----
__global__ void __launch_bounds__(256) k_g(const float* __restrict__ feats,
                                           const float* __restrict__ W1,
                                           const float* __restrict__ b1,
                                           uint4* __restrict__ Gh,
                                           const float* __restrict__ Ks,
                                           const float* __restrict__ poses,
                                           const int* __restrict__ ihp,
                                           const int* __restrict__ iwp,
                                           const float* __restrict__ W2,
                                           const float* __restrict__ b2,
                                           const float* __restrict__ W3,
                                           const float* __restrict__ b3,
                                           float* __restrict__ mats,
                                           _Float16* __restrict__ w2f,
                                           _Float16* __restrict__ w3f,
                                           float* __restrict__ b2f,
                                           float* __restrict__ b3f) {
    if (blockIdx.x == 2048) {
        int t = threadIdx.x;
        if (t < NVIEW * 12) {
            int v = t / 12, rc = t % 12, r = rc / 4, c = rc % 4;
            const float* K = Ks + v * 9;
            const float* P = poses + v * 12;
            float s = K[r*3+0]*P[0*4+c] + K[r*3+1]*P[1*4+c] + K[r*3+2]*P[2*4+c];
            float sc = (r == 0) ? 63.5f / (float)iwp[0]
                     : (r == 1) ? 63.5f / (float)ihp[0] : 1.0f;
            mats[v*12 + r*4 + c] = s * sc;
        }
        if (t < 64) {
            int n = t & 15, g = t >> 4;
            // B-frag for mfma_f32_16x16x32_f16: lane holds B[k=8g+j][n], j=0..7
#pragma unroll
            for (int jj = 0; jj < 8; jj++) {
                int kk = 8 * g + jj;
                w2f[t*8 + jj] = (_Float16)W2[kk * C2 + n];
                float w3v = (kk < C2 && n < C3) ? W3[kk * C3 + n] : 0.0f;  // K,N zero-pad
                w3f[t*8 + jj] = (_Float16)w3v;
            }
            b2f[t] = b2[n];
            b3f[t] = (n < C3) ? b3[n] : 0.0f;
        }
        return;
    }
    // 2048 blocks: [view(8)][group(4)][pixblk(64)]
    int bx = blockIdx.x;
    int pix = (bx & 63) * 256 + threadIdx.x;   // coalesced
    int grp = (bx >> 6) & 3;                   // 8-channel group
    int v   = bx >> 8;
    const float* fp = feats + ((size_t)v * CIN) * PLANE + pix;
    const float* W1g = W1 + grp * 8;
    float g[8];
#pragma unroll
    for (int jj = 0; jj < 8; jj++) g[jj] = b1[grp * 8 + jj];
#pragma unroll
    for (int c = 0; c < CIN; c++) {
        float fc = fp[(size_t)c * PLANE];
#pragma unroll
        for (int jj = 0; jj < 8; jj++) g[jj] = fmaf(fc, W1g[c*C1 + jj], g[jj]);
    }
    union { half2_t h2[4]; uint4 u; } pk;
#pragma unroll
    for (int q = 0; q < 4; q++) {
        half2_t p = { (_Float16)g[2*q], (_Float16)g[2*q+1] };   // RTNE
        pk.h2[q] = p;
    }
    Gh[((size_t)(v * 4 + grp)) * PLANE + pix] = pk.u;
}

// ---- K2: block = 4 independent waves; each wave = one 64-voxel column.
// Lane (m,g) gathers ONE uint4 (8 fp16 ch) per corner from plane-group g and
// blends with packed v_pk_fma_f16 straight into the MFMA A-frag.
// Layers 2+3 on MFMA; msum via ballot (fp32 projection, bit-exact mask). ----
__global__ void __launch_bounds__(256) k_main(
    const uint4* __restrict__ Gh,
    const float* __restrict__ mats, const float* __restrict__ bbox,
    const _Float16* __restrict__ w2f, const _Float16* __restrict__ w3f,
    const float* __restrict__ b2f, const float* __restrict__ b3f,
    float* __restrict__ out) {
#pragma clang fp contract(fast)
    __shared__ __align__(16) _Float16 h2s[4][64 * 24];   // per-wave [point][ch] slice

    int tid  = threadIdx.x;
    int wv   = tid >> 6;
    int lane = tid & 63;
    int col  = blockIdx.x * 4 + wv;        // 4096 columns: (k<<6)|j
    int j  = col & 63;
    int kz = col >> 6;
    _Float16* h2b = h2s[wv];

    int m = lane & 15, g = lane >> 4;
    float y = vox_coord(j, bbox[1]);
    float z = vox_coord(kz, bbox[2]);

    half8_t w2frag = *(const half8_t*)(w2f + lane * 8);
    half8_t w3frag = *(const half8_t*)(w3f + lane * 8);
    float b2c = b2f[lane];
    float b3c = b3f[lane];
    floatx4 cb2 = {b2c, b2c, b2c, b2c};
    floatx4 cb3 = {b3c, b3c, b3c, b3c};
    const half2_t z2 = { (_Float16)0.0f, (_Float16)0.0f };

    float M1[16], Msq[16], S16[16];
#pragma unroll
    for (int c = 0; c < 16; c++) { M1[c] = 0.0f; Msq[c] = 0.0f; S16[c] = 0.0f; }

#pragma unroll 1
    for (int v = 0; v < NVIEW; v++) {
        const float* M = mats + v * 12;
        const uint4* Gv = Gh + (size_t)(v * 4 + g) * PLANE;   // my 8-ch plane group

        floatx4 c2v[4];
        unsigned int ballo[4];
        int popc = 0;

#pragma unroll
        for (int T = 0; T < 4; T++) {
            int ipt = T * 16 + m;                      // point index in column
            float x = vox_coord(ipt, bbox[0]);
            float ix, iy, zc;
            proj_ixiy(M, x, y, z, ix, iy, zc);

            float fx0 = floorf(ix), fy0 = floorf(iy);
            float fx1 = fx0 + 1.0f, fy1 = fy0 + 1.0f;
            bool inb = (ix >= 0.0f) && (ix <= (float)(WF-1)) &&
                       (iy >= 0.0f) && (iy <= (float)(HF-1)) && (zc > 0.0f);
            int cx0 = (int)fminf(fmaxf(fx0, 0.0f), (float)(WF-1));
            int cx1 = (int)fminf(fmaxf(fx1, 0.0f), (float)(WF-1));
            int cy0 = (int)fminf(fmaxf(fy0, 0.0f), (float)(HF-1));
            int cy1 = (int)fminf(fmaxf(fy1, 0.0f), (float)(HF-1));
            float wnw = (fx1 - ix) * (fy1 - iy);
            float wne = (ix - fx0) * (fy1 - iy);
            float wsw = (fx1 - ix) * (iy - fy0);
            float wse = (ix - fx0) * (iy - fy0);

            unsigned long long bal = __ballot(inb);    // 4 identical copies per point
            ballo[T] = (unsigned int)bal;              // bits 0..15 = g-group 0
            popc += __popcll(bal);

            int t00 = cy0 * WF + cx0, t01 = cy0 * WF + cx1;
            int t10 = cy1 * WF + cx0, t11 = cy1 * WF + cx1;
            uint4 A = Gv[t00], B = Gv[t01], C = Gv[t10], D = Gv[t11];

            half2_t wnw2 = { (_Float16)wnw, (_Float16)wnw };   // RTNE
            half2_t wne2 = { (_Float16)wne, (_Float16)wne };
            half2_t wsw2 = { (_Float16)wsw, (_Float16)wsw };
            half2_t wse2 = { (_Float16)wse, (_Float16)wse };

            union { uint4 u; half2_t h[4]; } ua, ub, uc, ud;
            ua.u = A; ub.u = B; uc.u = C; ud.u = D;
            union { half2_t h2[4]; half8_t h8; } r;
#pragma unroll
            for (int c = 0; c < 4; c++) {
                half2_t e = ua.h[c]*wnw2 + ub.h[c]*wne2 + uc.h[c]*wsw2 + ud.h[c]*wse2;
                r.h2[c] = __builtin_elementwise_max(e, z2);    // relu, packed
            }

            c2v[T] = __builtin_amdgcn_mfma_f32_16x16x32_f16(r.h8, w2frag, cb2, 0, 0, 0);
        }

        // relu + cvt in C-layout (lane&15 = out-channel n), store h2 [pt][ch]
        wave_lds_sync();   // guard WAR vs previous view's h2 reads (cheap)
#pragma unroll
        for (int T = 0; T < 4; T++) {
#pragma unroll
            for (int r = 0; r < 4; r++) {
                float vv = fmaxf(c2v[T][r], 0.0f);
                h2b[(T*16 + g*4 + r) * 24 + m] = (_Float16)vv;
            }
        }
        wave_lds_sync();

        // layer 3: A = h2 rows (lane&15 = point-row), B = zero-padded W3, C = bias
        float msr = __builtin_amdgcn_rcpf((float)(popc >> 2) + 1e-8f);
#pragma unroll
        for (int T = 0; T < 4; T++) {
            half8_t a3 = *(const half8_t*)(h2b + (T*16 + m) * 24 + (g & 1) * 8);
            floatx4 c3 = __builtin_amdgcn_mfma_f32_16x16x32_f16(a3, w3frag, cb3, 0, 0, 0);
#pragma unroll
            for (int r = 0; r < 4; r++) {
                float w = ((ballo[T] >> (g*4 + r)) & 1u) ? msr : 0.0f;
                float val = c3[r];
                float t1 = w * val;
                S16[T*4+r] += w;
                M1[T*4+r]  += t1;
                Msq[T*4+r]  = fmaf(t1, val, Msq[T*4+r]);
            }
        }
    }

    // epilogue: lane (m<8, g) stores points T*16+g*4..+3, mean plane m, var plane m+8
    if (m < C3) {
        size_t base = (size_t)col * 64;
#pragma unroll
        for (int T = 0; T < 4; T++) {
            float4 mn, vr;
            mn.x = M1[T*4+0]; mn.y = M1[T*4+1]; mn.z = M1[T*4+2]; mn.w = M1[T*4+3];
            vr.x = fmaf(mn.x*mn.x, S16[T*4+0]-2.0f, Msq[T*4+0]);
            vr.y = fmaf(mn.y*mn.y, S16[T*4+1]-2.0f, Msq[T*4+1]);
            vr.z = fmaf(mn.z*mn.z, S16[T*4+2]-2.0f, Msq[T*4+2]);
            vr.w = fmaf(mn.w*mn.w, S16[T*4+3]-2.0f, Msq[T*4+3]);
            size_t ob = base + T*16 + g*4;
            *(float4*)(out + (size_t)m       * 262144 + ob) = mn;
            *(float4*)(out + (size_t)(m + 8) * 262144 + ob) = vr;
        }
    }
}

// ---- launch ----
extern "C" void kernel_launch(void* const* d_in, const int* in_sizes, int n_in,
                              void* d_out, int out_size, void* d_ws, size_t ws_size,
                              hipStream_t stream) {
    const float* feats = (const float*)d_in[0];
    const float* poses = (const float*)d_in[1];
    const float* Ks    = (const float*)d_in[2];
    const float* bbox  = (const float*)d_in[3];
    const int*   img_h = (const int*)d_in[4];
    const int*   img_w = (const int*)d_in[5];
    const float* W1    = (const float*)d_in[6];
    const float* b1    = (const float*)d_in[7];
    const float* W2    = (const float*)d_in[8];
    const float* b2    = (const float*)d_in[9];
    const float* W3    = (const float*)d_in[10];
    const float* b3    = (const float*)d_in[11];
    float* out = (float*)d_out;
    float* ws  = (float*)d_ws;

    float*     mats = ws;                        // 96 floats (pad to 128)
    _Float16*  w2f  = (_Float16*)(ws + 128);     // 512 halves (256 floats)
    _Float16*  w3f  = (_Float16*)(ws + 384);     // 512 halves
    float*     b2f  = ws + 640;                  // 64
    float*     b3f  = ws + 704;                  // 64
    uint4*     Gh   = (uint4*)(ws + 768);        // 8*4*16384 uint4 = 8.39 MB, 16B-aligned

    hipLaunchKernelGGL(k_g, dim3(2049), dim3(256), 0, stream,
                       feats, W1, b1, Gh, Ks, poses, img_h, img_w,
                       W2, b2, W3, b3, mats, w2f, w3f, b2f, b3f);
    hipLaunchKernelGGL(k_main, dim3(1024), dim3(256), 0, stream,
                       Gh, mats, bbox, w2f, w3f, b2f, b3f, out);
}

// Round 12
// 130.441 us; speedup vs baseline: 1.1705x; 1.0028x over previous
//
#include <hip/hip_runtime.h>
#include <math.h>

#define NVIEW 8
#define CIN   32
#define HF    128
#define WF    128
#define C1    32
#define C2    16
#define C3    8
#define RESO  64
#define PLANE (HF*WF)          // 16384 texels per (v,group) plane, uint4 units

typedef _Float16 half8_t  __attribute__((ext_vector_type(8)));
typedef _Float16 half2_t  __attribute__((ext_vector_type(2)));
typedef float    floatx4  __attribute__((ext_vector_type(4)));

static __device__ __forceinline__ float vox_coord(int idx, float b) {
    const float VOXEL = (float)(0.3 / 64.0);
    const float HALFV = (float)(0.3 / 128.0);
    return (float)idx * VOXEL + HALFV + b;
}

// wave-level LDS sync: each wave uses a private LDS slice; DS ops are in-order
// per wave, so only a lgkmcnt drain + compiler barrier is needed. No s_barrier.
static __device__ __forceinline__ void wave_lds_sync() {
    asm volatile("s_waitcnt lgkmcnt(0)" ::: "memory");
}

// ---- K1: G in fp16, planar 8-channel groups: Gh[(v*4+grp)*PLANE + pix] = 16 B
// (8 halves, RTNE). 4-way channel-split (thread = texel x 8 channels) +
// (block 2048) prep of mats / fp16 weight frags. ----
__global__ void __launch_bounds__(256) k_g(const float* __restrict__ feats,
                                           const float* __restrict__ W1,
                                           const float* __restrict__ b1,
                                           uint4* __restrict__ Gh,
                                           const float* __restrict__ Ks,
                                           const float* __restrict__ poses,
                                           const int* __restrict__ ihp,
                                           const int* __restrict__ iwp,
                                           const float* __restrict__ W2,
                                           const float* __restrict__ b2,
                                           const float* __restrict__ W3,
                                           const float* __restrict__ b3,
                                           float* __restrict__ mats,
                                           _Float16* __restrict__ w2f,
                                           _Float16* __restrict__ w3f,
                                           float* __restrict__ b2f,
                                           float* __restrict__ b3f) {
    if (blockIdx.x == 2048) {
        int t = threadIdx.x;
        if (t < NVIEW * 12) {
            int v = t / 12, rc = t % 12, r = rc / 4, c = rc % 4;
            const float* K = Ks + v * 9;
            const float* P = poses + v * 12;
            float s = K[r*3+0]*P[0*4+c] + K[r*3+1]*P[1*4+c] + K[r*3+2]*P[2*4+c];
            float sc = (r == 0) ? 63.5f / (float)iwp[0]
                     : (r == 1) ? 63.5f / (float)ihp[0] : 1.0f;
            mats[v*12 + r*4 + c] = s * sc;
        }
        if (t < 64) {
            int n = t & 15, g = t >> 4;
            // B-frag for mfma_f32_16x16x32_f16: lane holds B[k=8g+j][n], j=0..7
#pragma unroll
            for (int jj = 0; jj < 8; jj++) {
                int kk = 8 * g + jj;
                w2f[t*8 + jj] = (_Float16)W2[kk * C2 + n];
                float w3v = (kk < C2 && n < C3) ? W3[kk * C3 + n] : 0.0f;  // K,N zero-pad
                w3f[t*8 + jj] = (_Float16)w3v;
            }
            b2f[t] = b2[n];
            b3f[t] = (n < C3) ? b3[n] : 0.0f;
        }
        return;
    }
    // 2048 blocks: [view(8)][group(4)][pixblk(64)]
    int bx = blockIdx.x;
    int pix = (bx & 63) * 256 + threadIdx.x;   // coalesced
    int grp = (bx >> 6) & 3;                   // 8-channel group
    int v   = bx >> 8;
    const float* fp = feats + ((size_t)v * CIN) * PLANE + pix;
    const float* W1g = W1 + grp * 8;
    float g[8];
#pragma unroll
    for (int jj = 0; jj < 8; jj++) g[jj] = b1[grp * 8 + jj];
#pragma unroll
    for (int c = 0; c < CIN; c++) {
        float fc = fp[(size_t)c * PLANE];
#pragma unroll
        for (int jj = 0; jj < 8; jj++) g[jj] = fmaf(fc, W1g[c*C1 + jj], g[jj]);
    }
    union { half2_t h2[4]; uint4 u; } pk;
#pragma unroll
    for (int q = 0; q < 4; q++) {
        half2_t p = { (_Float16)g[2*q], (_Float16)g[2*q+1] };   // RTNE
        pk.h2[q] = p;
    }
    Gh[((size_t)(v * 4 + grp)) * PLANE + pix] = pk.u;
}

// ---- K2: block = 4 independent waves; each wave = one 64-voxel column.
// Lane (m,g) gathers ONE uint4 (8 fp16 ch) per corner from plane-group g and
// blends with packed v_pk_fma_f16 straight into the MFMA A-frag.
// Column-constant projection partials hoisted per view; view loop unrolled x2
// for cross-view load/compute overlap. Layers 2+3 on MFMA; msum via ballot. ----
__global__ void __launch_bounds__(256) k_main(
    const uint4* __restrict__ Gh,
    const float* __restrict__ mats, const float* __restrict__ bbox,
    const _Float16* __restrict__ w2f, const _Float16* __restrict__ w3f,
    const float* __restrict__ b2f, const float* __restrict__ b3f,
    float* __restrict__ out) {
#pragma clang fp contract(fast)
    __shared__ __align__(16) _Float16 h2s[4][64 * 24];   // per-wave [point][ch] slice

    int tid  = threadIdx.x;
    int wv   = tid >> 6;
    int lane = tid & 63;
    int col  = blockIdx.x * 4 + wv;        // 4096 columns: (k<<6)|j
    int j  = col & 63;
    int kz = col >> 6;
    _Float16* h2b = h2s[wv];

    int m = lane & 15, g = lane >> 4;
    float y = vox_coord(j, bbox[1]);
    float z = vox_coord(kz, bbox[2]);

    half8_t w2frag = *(const half8_t*)(w2f + lane * 8);
    half8_t w3frag = *(const half8_t*)(w3f + lane * 8);
    float b2c = b2f[lane];
    float b3c = b3f[lane];
    floatx4 cb2 = {b2c, b2c, b2c, b2c};
    floatx4 cb3 = {b3c, b3c, b3c, b3c};
    const half2_t z2 = { (_Float16)0.0f, (_Float16)0.0f };

    float M1[16], Msq[16], S16[16];
#pragma unroll
    for (int c = 0; c < 16; c++) { M1[c] = 0.0f; Msq[c] = 0.0f; S16[c] = 0.0f; }

#pragma unroll 2
    for (int v = 0; v < NVIEW; v++) {
        const float* M = mats + v * 12;
        const uint4* Gv = Gh + (size_t)(v * 4 + g) * PLANE;   // my 8-ch plane group

        // column constants: u = M0*x + Ku  (same association as reference:
        // M0*x + (M1*y + (M2*z + M3)) -> bit-identical to previous rounds)
        float Ku = fmaf(M[1], y, fmaf(M[2],  z, M[3]));
        float Kv = fmaf(M[5], y, fmaf(M[6],  z, M[7]));
        float Kz = fmaf(M[9], y, fmaf(M[10], z, M[11]));
        float M0 = M[0], M4 = M[4], M8 = M[8];

        floatx4 c2v[4];
        unsigned int ballo[4];
        int popc = 0;

#pragma unroll
        for (int T = 0; T < 4; T++) {
            int ipt = T * 16 + m;                      // point index in column
            float x = vox_coord(ipt, bbox[0]);
            float u  = fmaf(M0, x, Ku);
            float vv = fmaf(M4, x, Kv);
            float zc = fmaf(M8, x, Kz);
            float invz = __builtin_amdgcn_rcpf(zc);
            float ix = u * invz;
            float iy = vv * invz;

            float fx0 = floorf(ix), fy0 = floorf(iy);
            float fx1 = fx0 + 1.0f, fy1 = fy0 + 1.0f;
            bool inb = (ix >= 0.0f) && (ix <= (float)(WF-1)) &&
                       (iy >= 0.0f) && (iy <= (float)(HF-1)) && (zc > 0.0f);
            int cx0 = (int)fminf(fmaxf(fx0, 0.0f), (float)(WF-1));
            int cx1 = (int)fminf(fmaxf(fx1, 0.0f), (float)(WF-1));
            int cy0 = (int)fminf(fmaxf(fy0, 0.0f), (float)(HF-1));
            int cy1 = (int)fminf(fmaxf(fy1, 0.0f), (float)(HF-1));
            float wnw = (fx1 - ix) * (fy1 - iy);
            float wne = (ix - fx0) * (fy1 - iy);
            float wsw = (fx1 - ix) * (iy - fy0);
            float wse = (ix - fx0) * (iy - fy0);

            unsigned long long bal = __ballot(inb);    // 4 identical copies per point
            ballo[T] = (unsigned int)bal;              // bits 0..15 = g-group 0
            popc += __popcll(bal);

            int t00 = cy0 * WF + cx0, t01 = cy0 * WF + cx1;
            int t10 = cy1 * WF + cx0, t11 = cy1 * WF + cx1;
            uint4 A = Gv[t00], B = Gv[t01], C = Gv[t10], D = Gv[t11];

            half2_t wnw2 = { (_Float16)wnw, (_Float16)wnw };   // RTNE
            half2_t wne2 = { (_Float16)wne, (_Float16)wne };
            half2_t wsw2 = { (_Float16)wsw, (_Float16)wsw };
            half2_t wse2 = { (_Float16)wse, (_Float16)wse };

            union { uint4 u; half2_t h[4]; } ua, ub, uc, ud;
            ua.u = A; ub.u = B; uc.u = C; ud.u = D;
            union { half2_t h2[4]; half8_t h8; } r;
#pragma unroll
            for (int c = 0; c < 4; c++) {
                half2_t e = ua.h[c]*wnw2 + ub.h[c]*wne2 + uc.h[c]*wsw2 + ud.h[c]*wse2;
                r.h2[c] = __builtin_elementwise_max(e, z2);    // relu, packed
            }

            c2v[T] = __builtin_amdgcn_mfma_f32_16x16x32_f16(r.h8, w2frag, cb2, 0, 0, 0);
        }

        // relu + cvt in C-layout (lane&15 = out-channel n), store h2 [pt][ch]
        wave_lds_sync();   // guard WAR vs previous view's h2 reads (cheap)
#pragma unroll
        for (int T = 0; T < 4; T++) {
#pragma unroll
            for (int r = 0; r < 4; r++) {
                float vv = fmaxf(c2v[T][r], 0.0f);
                h2b[(T*16 + g*4 + r) * 24 + m] = (_Float16)vv;
            }
        }
        wave_lds_sync();

        // layer 3: A = h2 rows (lane&15 = point-row), B = zero-padded W3, C = bias
        float msr = __builtin_amdgcn_rcpf((float)(popc >> 2) + 1e-8f);
#pragma unroll
        for (int T = 0; T < 4; T++) {
            half8_t a3 = *(const half8_t*)(h2b + (T*16 + m) * 24 + (g & 1) * 8);
            floatx4 c3 = __builtin_amdgcn_mfma_f32_16x16x32_f16(a3, w3frag, cb3, 0, 0, 0);
#pragma unroll
            for (int r = 0; r < 4; r++) {
                float w = ((ballo[T] >> (g*4 + r)) & 1u) ? msr : 0.0f;
                float val = c3[r];
                float t1 = w * val;
                S16[T*4+r] += w;
                M1[T*4+r]  += t1;
                Msq[T*4+r]  = fmaf(t1, val, Msq[T*4+r]);
            }
        }
    }

    // epilogue: lane (m<8, g) stores points T*16+g*4..+3, mean plane m, var plane m+8
    if (m < C3) {
        size_t base = (size_t)col * 64;
#pragma unroll
        for (int T = 0; T < 4; T++) {
            float4 mn, vr;
            mn.x = M1[T*4+0]; mn.y = M1[T*4+1]; mn.z = M1[T*4+2]; mn.w = M1[T*4+3];
            vr.x = fmaf(mn.x*mn.x, S16[T*4+0]-2.0f, Msq[T*4+0]);
            vr.y = fmaf(mn.y*mn.y, S16[T*4+1]-2.0f, Msq[T*4+1]);
            vr.z = fmaf(mn.z*mn.z, S16[T*4+2]-2.0f, Msq[T*4+2]);
            vr.w = fmaf(mn.w*mn.w, S16[T*4+3]-2.0f, Msq[T*4+3]);
            size_t ob = base + T*16 + g*4;
            *(float4*)(out + (size_t)m       * 262144 + ob) = mn;
            *(float4*)(out + (size_t)(m + 8) * 262144 + ob) = vr;
        }
    }
}

// ---- launch ----
extern "C" void kernel_launch(void* const* d_in, const int* in_sizes, int n_in,
                              void* d_out, int out_size, void* d_ws, size_t ws_size,
                              hipStream_t stream) {
    const float* feats = (const float*)d_in[0];
    const float* poses = (const float*)d_in[1];
    const float* Ks    = (const float*)d_in[2];
    const float* bbox  = (const float*)d_in[3];
    const int*   img_h = (const int*)d_in[4];
    const int*   img_w = (const int*)d_in[5];
    const float* W1    = (const float*)d_in[6];
    const float* b1    = (const float*)d_in[7];
    const float* W2    = (const float*)d_in[8];
    const float* b2    = (const float*)d_in[9];
    const float* W3    = (const float*)d_in[10];
    const float* b3    = (const float*)d_in[11];
    float* out = (float*)d_out;
    float* ws  = (float*)d_ws;

    float*     mats = ws;                        // 96 floats (pad to 128)
    _Float16*  w2f  = (_Float16*)(ws + 128);     // 512 halves (256 floats)
    _Float16*  w3f  = (_Float16*)(ws + 384);     // 512 halves
    float*     b2f  = ws + 640;                  // 64
    float*     b3f  = ws + 704;                  // 64
    uint4*     Gh   = (uint4*)(ws + 768);        // 8*4*16384 uint4 = 8.39 MB, 16B-aligned

    hipLaunchKernelGGL(k_g, dim3(2049), dim3(256), 0, stream,
                       feats, W1, b1, Gh, Ks, poses, img_h, img_w,
                       W2, b2, W3, b3, mats, w2f, w3f, b2f, b3f);
    hipLaunchKernelGGL(k_main, dim3(1024), dim3(256), 0, stream,
                       Gh, mats, bbox, w2f, w3f, b2f, b3f, out);
}